// Round 9
// baseline (160.840 us; speedup 1.0000x reference)
//
#include <hip/hip_runtime.h>
#include <hip/hip_cooperative_groups.h>

namespace cg = cooperative_groups;

#define Bn 4
#define Qn 1024
#define Kn 1024
#define Dd 256
#define Hh 64
#define Dv 256
#define TQ 16

typedef __attribute__((ext_vector_type(8))) short short8;
typedef __attribute__((ext_vector_type(8))) _Float16 half8;
typedef __attribute__((ext_vector_type(4))) float floatx4;
typedef __attribute__((ext_vector_type(2))) float floatx2;
typedef __attribute__((ext_vector_type(16))) float floatx16;

__device__ __forceinline__ floatx2 fma2(floatx2 a, floatx2 b, floatx2 c) {
    return __builtin_elementwise_fma(a, b, c);
}
__device__ __forceinline__ floatx2 mk2(float x, float y) {
    floatx2 r; r.x = x; r.y = y; return r;
}

__device__ __forceinline__ short f32_to_bf16(float x) {
    unsigned u = __float_as_uint(x);
    unsigned r = u + 0x7fffu + ((u >> 16) & 1u);   // RNE
    return (short)(r >> 16);
}
__device__ __forceinline__ float bf16_to_f32(short h) {
    return __uint_as_float(((unsigned)(unsigned short)h) << 16);
}

// R26: single cooperative kernel = prep phase + grid.sync + attn phase.
// Theory: prep measured 24-30us across FIVE different structures with a
// ~2us issue/byte floor -> the cost is per-dispatch overhead (~8-10us
// launch+gap, per rocprof.md), not kernel internals. Merging prep+attn
// removes one dispatch+gap AND finally exposes the combined counters.
//   Phase A: 2560 wave-jobs (2048 proj [v8 streamed, <=128 VGPR for the
//            1024-thread shape] + 512 V-swizzle), 10 jobs/block.
//   grid.sync() (device-scope fences; harness supports coop launch)
//   + s_dcache_inv: phase B s_loads Eqt written by phase A on other XCDs;
//     scalar L1 is not invalidated by vector-path fences.
//   Phase B: R8 attn verbatim (Eqt transposed q reads, fp16 split-P AV).
__global__ __launch_bounds__(1024) void fused_kernel(const float* __restrict__ Xq,
                                                     const float* __restrict__ Wq,
                                                     const float* __restrict__ Xk,
                                                     const float* __restrict__ Wk,
                                                     const float* __restrict__ V,
                                                     const float* __restrict__ wv,
                                                     float* __restrict__ Eqt,
                                                     float* __restrict__ Ekt,
                                                     _Float16* __restrict__ Vh,
                                                     float* __restrict__ out) {
    __shared__ __align__(16) unsigned sc[TQ * 1028];   // 65.8 KB: P hi/lo fp16
    __shared__ float wsum[16 * TQ];

    // ================= Phase A: prep (waves 0..9 of each block) =================
    {
        int wave = threadIdx.x >> 6, l = threadIdx.x & 63;
        int job = blockIdx.x * 10 + wave;              // 256*10 = 2560 jobs exactly
        if (wave < 10) {
            if (job < 2048) {
                // ---- projection wave-job: 16x16 output tile, K=256 streamed ----
                int bo = job >> 2;                     // 0..511
                int side = bo >> 8;                    // 0: q, 1: k
                int r0 = (bo & 255) * 16;
                int ct = job & 3;
                const float* X = side ? Xk : Xq;
                const float* W = side ? Wk : Wq;
                const float* xrow = X + (size_t)(r0 + (l & 15)) * Dd + (l >> 4) * 8;
                const float* wcol = W + (size_t)((l >> 4) * 8) * Hh + ct * 16 + (l & 15);

                floatx4 sxa[2], sxb[2];
                float swr[2][8];
#define PLOAD(kt, s) do {                                                   \
                    sxa[s] = *(const floatx4*)(xrow + (kt) * 32);           \
                    sxb[s] = *(const floatx4*)(xrow + (kt) * 32 + 4);       \
                    _Pragma("unroll")                                       \
                    for (int j = 0; j < 8; ++j)                             \
                        swr[s][j] = wcol[(size_t)((kt) * 32 + j) * Hh];     \
                } while (0)

                PLOAD(0, 0);
                floatx4 acc = {0.f, 0.f, 0.f, 0.f};
                #pragma unroll
                for (int kt = 0; kt < 8; ++kt) {
                    int cur = kt & 1;
                    if (kt < 7) PLOAD(kt + 1, 1 - cur);   // prefetch next stage
                    short8 ah, al, wh, wl;
                    #pragma unroll
                    for (int j = 0; j < 4; ++j) {
                        short hs = f32_to_bf16(sxa[cur][j]);
                        ah[j] = hs;
                        al[j] = f32_to_bf16(sxa[cur][j] - bf16_to_f32(hs));
                        short hs2 = f32_to_bf16(sxb[cur][j]);
                        ah[j + 4] = hs2;
                        al[j + 4] = f32_to_bf16(sxb[cur][j] - bf16_to_f32(hs2));
                    }
                    #pragma unroll
                    for (int j = 0; j < 8; ++j) {
                        short hs = f32_to_bf16(swr[cur][j]);
                        wh[j] = hs;
                        wl[j] = f32_to_bf16(swr[cur][j] - bf16_to_f32(hs));
                    }
                    acc = __builtin_amdgcn_mfma_f32_16x16x32_bf16(ah, wh, acc, 0, 0, 0);
                    acc = __builtin_amdgcn_mfma_f32_16x16x32_bf16(al, wh, acc, 0, 0, 0);
                    acc = __builtin_amdgcn_mfma_f32_16x16x32_bf16(ah, wl, acc, 0, 0, 0);
                }
#undef PLOAD
                // ---- epilogue: exp-fold, transposed float4 store ----
                int h = ct * 16 + (l & 15);
                float e0 = __expf(2.f * acc[0]);
                float e1 = __expf(2.f * acc[1]);
                float e2 = __expf(2.f * acc[2]);
                float e3 = __expf(2.f * acc[3]);
                int row0g = r0 + (l >> 4) * 4;         // reg i -> consecutive rows
                int bb = row0g >> 10, k0 = row0g & 1023;
                float* Edst = side ? Ekt : Eqt;
                float4 o = { e0, e1, e2, e3 };
                *(float4*)(Edst + ((size_t)(bb * Hh + h)) * Kn + k0) = o;
            } else {
                // ---- V-swizzle wave-job ----
                int vjob = job - 2048;                 // 0..511
                int vblk = vjob >> 2;
                int wv_ = vjob & 3;
                int bb = vblk >> 5, kt = vblk & 31;
                const float* Vg = V + ((size_t)(bb * Kn + kt * 32 + (l >> 4) * 8)) * Dv + (l & 15);
                #pragma unroll
                for (int p = 0; p < 4; ++p) {
                    int nt = wv_ * 4 + p;
                    const float* vp = Vg + nt * 16;
                    half8 hv;
                    #pragma unroll
                    for (int j = 0; j < 8; ++j)
                        hv[j] = (_Float16)vp[(size_t)j * Dv];
                    size_t base = (((size_t)(bb * 32 + kt) * 16 + nt) * 512) + (size_t)l * 8;
                    *(half8*)(Vh + base) = hv;
                }
            }
        }
    }

    cg::this_grid().sync();
    // Scalar-cache guard: phase B reads Eqt via s_load; sL1 is not covered
    // by the vector-path acquire fences in grid.sync().
    asm volatile("s_dcache_inv" ::: "memory");

    // ================= Phase B: attn (R8 kernel verbatim) =================
    int tid = threadIdx.x;
    int blk = blockIdx.x;
    // XCD swizzle: blk%8 = XCD; batch b pinned to XCDs {2b,2b+1}.
    int b = (blk & 7) >> 1;
    int tile = (blk >> 3) * 2 + (blk & 1);   // 0..63, bijective per batch
    int qbase = tile * TQ;

    const float* kb = Ekt + (size_t)b * Hh * Kn;
    const float* qt = Eqt + (size_t)b * Hh * Qn + qbase;   // [h][q] rows
    const float4* wv4 = (const float4*)wv;
    floatx2 s2[TQ / 2];
    #pragma unroll
    for (int i = 0; i < TQ / 2; ++i) { s2[i].x = 0.f; s2[i].y = 0.f; }

    float e0 = kb[0 * Kn + tid];
    float e1 = kb[1 * Kn + tid];
    float e2 = kb[2 * Kn + tid];
    float e3 = kb[3 * Kn + tid];
    floatx2 one2 = mk2(1.f, 1.f);
    for (int h4 = 0; h4 < Hh / 4; ++h4) {
        float n0, n1, n2, n3;
        if (h4 < Hh / 4 - 1) {                 // prefetch next iteration
            const float* kn = kb + (h4 + 1) * 4 * Kn;
            n0 = kn[0 * Kn + tid];
            n1 = kn[1 * Kn + tid];
            n2 = kn[2 * Kn + tid];
            n3 = kn[3 * Kn + tid];
        }
        float4 w4 = wv4[h4];                                   // s_load
        floatx16 q0 = *(const floatx16*)(qt + (size_t)(h4 * 4 + 0) * Qn);  // s_load x16
        floatx16 q1 = *(const floatx16*)(qt + (size_t)(h4 * 4 + 1) * Qn);
        floatx16 q2 = *(const floatx16*)(qt + (size_t)(h4 * 4 + 2) * Qn);
        floatx16 q3 = *(const floatx16*)(qt + (size_t)(h4 * 4 + 3) * Qn);
        floatx2 e0s = mk2(e0, e0), e1s = mk2(e1, e1);
        floatx2 e2s = mk2(e2, e2), e3s = mk2(e3, e3);
        floatx2 wx = mk2(w4.x, w4.x), wy = mk2(w4.y, w4.y);
        floatx2 wz = mk2(w4.z, w4.z), ww = mk2(w4.w, w4.w);
        #pragma unroll
        for (int qq = 0; qq < TQ; qq += 2) {
            floatx2 A = fma2(mk2(q0[qq], q0[qq + 1]), e0s, one2);
            floatx2 B = fma2(mk2(q1[qq], q1[qq + 1]), e1s, one2);
            floatx2 C = fma2(mk2(q2[qq], q2[qq + 1]), e2s, one2);
            floatx2 D = fma2(mk2(q3[qq], q3[qq + 1]), e3s, one2);
            floatx2 AB = A * B;
            floatx2 CD = C * D;
            floatx2 ABCD = AB * CD;
            floatx2 NAB = fma2(wx, B, wy * A);
            floatx2 NCD = fma2(wz, D, ww * C);
            floatx2 NUM = fma2(NCD, AB, NAB * CD);
            floatx2 R = mk2(__builtin_amdgcn_rcpf(ABCD.x),
                            __builtin_amdgcn_rcpf(ABCD.y));
            s2[qq >> 1] = fma2(NUM, R, s2[qq >> 1]);
        }
        e0 = n0; e1 = n1; e2 = n2; e3 = n3;
    }

    int wave = tid >> 6, lane = tid & 63;
    // ---- V prefetch for kt=0: P-independent, hides under exp/pack/barrier ----
    size_t vb0 = (((size_t)(b * 32) * 16 + wave) * 512) + (size_t)lane * 8;
    half8 vcur = *(const half8*)(Vh + vb0);

    // p = exp(-2s); write fp16 hi/lo; per-q wave partials (fp32 p).
    _Float16* sp = (_Float16*)sc;
    float part[TQ];
    #pragma unroll
    for (int q = 0; q < TQ; ++q) {
        float sq = (q & 1) ? s2[q >> 1].y : s2[q >> 1].x;
        float p = __expf(-2.f * sq);
        part[q] = p;
        _Float16 hs = (_Float16)p;
        sp[q * 2056 + tid] = hs;
        sp[q * 2056 + 1024 + tid] = (_Float16)(p - (float)hs);
    }

    #pragma unroll
    for (int q = 0; q < TQ; ++q) {
        #pragma unroll
        for (int off = 32; off >= 1; off >>= 1)
            part[q] += __shfl_xor(part[q], off, 64);
    }
    if (lane == 0) {
        #pragma unroll
        for (int q = 0; q < TQ; ++q) wsum[wave * TQ + q] = part[q];
    }
    __syncthreads();

    // ---- AV via fp16 MFMA, software-pipelined V; wave owns ntile = wave ----
    int qf = lane & 15, kc = lane >> 4;
    floatx4 acc = {0.f, 0.f, 0.f, 0.f};
    const char* scb = (const char*)sc + qf * 4112 + kc * 16;
    #pragma unroll 2
    for (int kt = 0; kt < 31; ++kt) {
        half8 vnext = *(const half8*)(Vh + vb0 + (size_t)(kt + 1) * 8192);
        half8 bhi = *(const half8*)(scb + kt * 64);
        half8 blo = *(const half8*)(scb + 2048 + kt * 64);
        acc = __builtin_amdgcn_mfma_f32_16x16x32_f16(vcur, bhi, acc, 0, 0, 0);
        acc = __builtin_amdgcn_mfma_f32_16x16x32_f16(vcur, blo, acc, 0, 0, 0);
        vcur = vnext;
    }
    {
        half8 bhi = *(const half8*)(scb + 31 * 64);
        half8 blo = *(const half8*)(scb + 2048 + 31 * 64);
        acc = __builtin_amdgcn_mfma_f32_16x16x32_f16(vcur, bhi, acc, 0, 0, 0);
        acc = __builtin_amdgcn_mfma_f32_16x16x32_f16(vcur, blo, acc, 0, 0, 0);
    }
    {
        float vsum = 0.f;
        #pragma unroll
        for (int w = 0; w < 16; ++w) vsum += wsum[w * TQ + qf];
        float r = 1.f / vsum;
        float* ob = out + ((size_t)(b * Qn + qbase + qf)) * Dv + wave * 16 + kc * 4;
        float4 o = { acc[0] * r, acc[1] * r, acc[2] * r, acc[3] * r };
        *(float4*)ob = o;
    }
}

extern "C" void kernel_launch(void* const* d_in, const int* in_sizes, int n_in,
                              void* d_out, int out_size, void* d_ws, size_t ws_size,
                              hipStream_t stream) {
    const float* queries = (const float*)d_in[0];
    const float* keys    = (const float*)d_in[1];
    const float* values  = (const float*)d_in[2];
    const float* W_q     = (const float*)d_in[3];
    const float* W_k     = (const float*)d_in[4];
    const float* w_v     = (const float*)d_in[5];
    float* out = (float*)d_out;

    float* Eqt = (float*)d_ws;                      // [B, H, Q]     1 MB
    float* Ekt = Eqt + Bn * Qn * Hh;                // [B, H, K]     1 MB
    _Float16* Vh = (_Float16*)(Ekt + Bn * Kn * Hh); // frag-order    2 MB

    void* args[] = { (void*)&queries, (void*)&W_q, (void*)&keys, (void*)&W_k,
                     (void*)&values,  (void*)&w_v, (void*)&Eqt,  (void*)&Ekt,
                     (void*)&Vh, (void*)&out };
    hipLaunchCooperativeKernel((const void*)fused_kernel, dim3(256), dim3(1024),
                               args, 0, stream);
}

// Round 10
// 105.996 us; speedup vs baseline: 1.5174x; 1.5174x over previous
//
#include <hip/hip_runtime.h>

#define Bn 4
#define Qn 1024
#define Kn 1024
#define Dd 256
#define Hh 64
#define Dv 256
#define TQ 16

typedef __attribute__((ext_vector_type(8))) short short8;
typedef __attribute__((ext_vector_type(8))) _Float16 half8;
typedef __attribute__((ext_vector_type(4))) float floatx4;
typedef __attribute__((ext_vector_type(2))) float floatx2;
typedef __attribute__((ext_vector_type(16))) float floatx16;

__device__ __forceinline__ floatx2 fma2(floatx2 a, floatx2 b, floatx2 c) {
    return __builtin_elementwise_fma(a, b, c);
}
__device__ __forceinline__ floatx2 mk2(float x, float y) {
    floatx2 r; r.x = x; r.y = y; return r;
}

__device__ __forceinline__ short f32_to_bf16(float x) {
    unsigned u = __float_as_uint(x);
    unsigned r = u + 0x7fffu + ((u >> 16) & 1u);   // RNE
    return (short)(r >> 16);
}
__device__ __forceinline__ float bf16_to_f32(short h) {
    return __uint_as_float(((unsigned)(unsigned short)h) << 16);
}

// Fused prep v7t + R27 fix: __launch_bounds__(256, 1).
// R9's fused kernel exposed VGPR_Count=52 — with no min-waves arg the
// compiler clamps VGPRs for occupancy the 640-block grid can never use
// (2.5 waves/SIMD, grid-limited), so v7's ~280 live registers (16 in-flight
// b128 X loads + 64 W floats + 4 frag arrays) spilled to scratch in EVERY
// prior prep variant — explaining the structure-invariant ~25us. (256,1)
// raises the budget to 512: no spills, all loads genuinely in flight,
// zero occupancy cost.
//  blocks 0..511  : proj (side=blk>>8, row-tile=(blk&255)*16, wave ct)
//  blocks 512..639: V -> fp16 A-frag swizzle
__global__ __launch_bounds__(256, 1) void prep_kernel(const float* __restrict__ Xq,
                                                      const float* __restrict__ Wq,
                                                      const float* __restrict__ Xk,
                                                      const float* __restrict__ Wk,
                                                      const float* __restrict__ V,
                                                      float* __restrict__ Eqt,
                                                      float* __restrict__ Ekt,
                                                      _Float16* __restrict__ Vh) {
    int t = threadIdx.x;
    int wave = t >> 6, l = t & 63;
    if (blockIdx.x < 512) {
        int side = blockIdx.x >> 8;              // 0: q, 1: k
        int r0 = (blockIdx.x & 255) * 16;        // row tile within side
        int ct = wave;                           // 16-col slice of H
        const float* X = side ? Xk : Xq;
        const float* W = side ? Wk : Wq;
        // ---- X loads (issued first, all in flight) ----
        const float* xrow = X + (size_t)(r0 + (l & 15)) * Dd + (l >> 4) * 8;
        floatx4 xa[8], xb[8];
        #pragma unroll
        for (int kt = 0; kt < 8; ++kt) {
            xa[kt] = *(const floatx4*)(xrow + kt * 32);
            xb[kt] = *(const floatx4*)(xrow + kt * 32 + 4);
        }
        // ---- W slice gather: 64 scalar loads, 4x64B lines per instr ----
        float wraw[8][8];
        #pragma unroll
        for (int kt = 0; kt < 8; ++kt) {
            const float* wp = W + (size_t)(kt * 32 + (l >> 4) * 8) * Hh + ct * 16 + (l & 15);
            #pragma unroll
            for (int j = 0; j < 8; ++j) wraw[kt][j] = wp[j * Hh];
        }
        // ---- split-bf16 fragments ----
        short8 ah[8], al[8], wh[8], wl[8];
        #pragma unroll
        for (int kt = 0; kt < 8; ++kt) {
            #pragma unroll
            for (int j = 0; j < 4; ++j) {
                short hs = f32_to_bf16(xa[kt][j]);
                ah[kt][j] = hs;
                al[kt][j] = f32_to_bf16(xa[kt][j] - bf16_to_f32(hs));
                short hs2 = f32_to_bf16(xb[kt][j]);
                ah[kt][j + 4] = hs2;
                al[kt][j + 4] = f32_to_bf16(xb[kt][j] - bf16_to_f32(hs2));
            }
            #pragma unroll
            for (int j = 0; j < 8; ++j) {
                short hs = f32_to_bf16(wraw[kt][j]);
                wh[kt][j] = hs;
                wl[kt][j] = f32_to_bf16(wraw[kt][j] - bf16_to_f32(hs));
            }
        }
        floatx4 acc = {0.f, 0.f, 0.f, 0.f};
        #pragma unroll
        for (int kt = 0; kt < 8; ++kt) {
            acc = __builtin_amdgcn_mfma_f32_16x16x32_bf16(ah[kt], wh[kt], acc, 0, 0, 0);
            acc = __builtin_amdgcn_mfma_f32_16x16x32_bf16(al[kt], wh[kt], acc, 0, 0, 0);
            acc = __builtin_amdgcn_mfma_f32_16x16x32_bf16(ah[kt], wl[kt], acc, 0, 0, 0);
        }
        // ---- epilogue: exp-fold and transposed store (both sides) ----
        int h = ct * 16 + (l & 15);
        float e0 = __expf(2.f * acc[0]);
        float e1 = __expf(2.f * acc[1]);
        float e2 = __expf(2.f * acc[2]);
        float e3 = __expf(2.f * acc[3]);
        int row0g = r0 + (l >> 4) * 4;           // reg i -> consecutive rows
        float* Edst = side ? Ekt : Eqt;
        int bb = row0g >> 10, k0 = row0g & 1023;
        float4 o = { e0, e1, e2, e3 };
        *(float4*)(Edst + ((size_t)(bb * Hh + h)) * Kn + k0) = o;  // 16 full lines/instr
    } else {
        int vblk = blockIdx.x - 512;
        int b = vblk >> 5;
        int kt = vblk & 31;
        const float* Vg = V + ((size_t)(b * Kn + kt * 32 + (l >> 4) * 8)) * Dv + (l & 15);
        #pragma unroll
        for (int p = 0; p < 4; ++p) {
            int nt = wave * 4 + p;
            const float* vp = Vg + nt * 16;
            half8 hv;
            #pragma unroll
            for (int j = 0; j < 8; ++j)
                hv[j] = (_Float16)vp[(size_t)j * Dv];
            size_t base = (((size_t)(b * 32 + kt) * 16 + nt) * 512) + (size_t)l * 8;
            *(half8*)(Vh + base) = hv;
        }
    }
}

// score(q,k) = W_sum - 2*sum_h w_h/(Eq_h*Ek_h+1); W_sum cancels in softmax.
// R27: attn = R8 verbatim (best measured: ~40us). Eqt transposed q reads
// (4x s_load_dwordx16 + 1 dwordx4 per h4-iter), fp16 split-P AV with
// software-pipelined V, single barrier, per-thread finalize.
__global__ __launch_bounds__(1024, 4) void attn_kernel(const float* __restrict__ Eqt,
                                                       const float* __restrict__ Ekt,
                                                       const _Float16* __restrict__ Vh,
                                                       const float* __restrict__ wv,
                                                       float* __restrict__ out) {
    __shared__ __align__(16) unsigned sc[TQ * 1028];   // 65.8 KB: P hi/lo fp16
    __shared__ float wsum[16 * TQ];

    int tid = threadIdx.x;
    int blk = blockIdx.x;
    // XCD swizzle: blk%8 = XCD; batch b pinned to XCDs {2b,2b+1}.
    int b = (blk & 7) >> 1;
    int tile = (blk >> 3) * 2 + (blk & 1);   // 0..63, bijective per batch
    int qbase = tile * TQ;

    // ---- score phase: thread owns k = tid; q-pairs packed as float2 ----
    const float* kb = Ekt + (size_t)b * Hh * Kn;
    const float* qt = Eqt + (size_t)b * Hh * Qn + qbase;   // [h][q] rows
    const float4* wv4 = (const float4*)wv;
    floatx2 s2[TQ / 2];
    #pragma unroll
    for (int i = 0; i < TQ / 2; ++i) { s2[i].x = 0.f; s2[i].y = 0.f; }

    float e0 = kb[0 * Kn + tid];
    float e1 = kb[1 * Kn + tid];
    float e2 = kb[2 * Kn + tid];
    float e3 = kb[3 * Kn + tid];
    floatx2 one2 = mk2(1.f, 1.f);
    for (int h4 = 0; h4 < Hh / 4; ++h4) {
        float n0, n1, n2, n3;
        if (h4 < Hh / 4 - 1) {                 // prefetch next iteration
            const float* kn = kb + (h4 + 1) * 4 * Kn;
            n0 = kn[0 * Kn + tid];
            n1 = kn[1 * Kn + tid];
            n2 = kn[2 * Kn + tid];
            n3 = kn[3 * Kn + tid];
        }
        float4 w4 = wv4[h4];                                   // s_load
        floatx16 q0 = *(const floatx16*)(qt + (size_t)(h4 * 4 + 0) * Qn);  // s_load x16
        floatx16 q1 = *(const floatx16*)(qt + (size_t)(h4 * 4 + 1) * Qn);
        floatx16 q2 = *(const floatx16*)(qt + (size_t)(h4 * 4 + 2) * Qn);
        floatx16 q3 = *(const floatx16*)(qt + (size_t)(h4 * 4 + 3) * Qn);
        floatx2 e0s = mk2(e0, e0), e1s = mk2(e1, e1);
        floatx2 e2s = mk2(e2, e2), e3s = mk2(e3, e3);
        floatx2 wx = mk2(w4.x, w4.x), wy = mk2(w4.y, w4.y);
        floatx2 wz = mk2(w4.z, w4.z), ww = mk2(w4.w, w4.w);
        #pragma unroll
        for (int qq = 0; qq < TQ; qq += 2) {
            floatx2 A = fma2(mk2(q0[qq], q0[qq + 1]), e0s, one2);
            floatx2 B = fma2(mk2(q1[qq], q1[qq + 1]), e1s, one2);
            floatx2 C = fma2(mk2(q2[qq], q2[qq + 1]), e2s, one2);
            floatx2 D = fma2(mk2(q3[qq], q3[qq + 1]), e3s, one2);
            floatx2 AB = A * B;
            floatx2 CD = C * D;
            floatx2 ABCD = AB * CD;
            floatx2 NAB = fma2(wx, B, wy * A);
            floatx2 NCD = fma2(wz, D, ww * C);
            floatx2 NUM = fma2(NCD, AB, NAB * CD);
            floatx2 R = mk2(__builtin_amdgcn_rcpf(ABCD.x),
                            __builtin_amdgcn_rcpf(ABCD.y));
            s2[qq >> 1] = fma2(NUM, R, s2[qq >> 1]);
        }
        e0 = n0; e1 = n1; e2 = n2; e3 = n3;
    }

    int wave = tid >> 6, lane = tid & 63;
    // ---- V prefetch for kt=0: P-independent, hides under exp/pack/barrier ----
    size_t vb0 = (((size_t)(b * 32) * 16 + wave) * 512) + (size_t)lane * 8;
    half8 vcur = *(const half8*)(Vh + vb0);

    // p = exp(-2s); write fp16 hi/lo; per-q wave partials (fp32 p).
    _Float16* sp = (_Float16*)sc;
    float part[TQ];
    #pragma unroll
    for (int q = 0; q < TQ; ++q) {
        float sq = (q & 1) ? s2[q >> 1].y : s2[q >> 1].x;
        float p = __expf(-2.f * sq);
        part[q] = p;
        _Float16 hs = (_Float16)p;
        sp[q * 2056 + tid] = hs;
        sp[q * 2056 + 1024 + tid] = (_Float16)(p - (float)hs);
    }

    #pragma unroll
    for (int q = 0; q < TQ; ++q) {
        #pragma unroll
        for (int off = 32; off >= 1; off >>= 1)
            part[q] += __shfl_xor(part[q], off, 64);
    }
    if (lane == 0) {
        #pragma unroll
        for (int q = 0; q < TQ; ++q) wsum[wave * TQ + q] = part[q];
    }
    __syncthreads();

    // ---- AV via fp16 MFMA, software-pipelined V; wave owns ntile = wave ----
    int qf = lane & 15, kc = lane >> 4;
    floatx4 acc = {0.f, 0.f, 0.f, 0.f};
    const char* scb = (const char*)sc + qf * 4112 + kc * 16;
    #pragma unroll 2
    for (int kt = 0; kt < 31; ++kt) {
        half8 vnext = *(const half8*)(Vh + vb0 + (size_t)(kt + 1) * 8192);
        half8 bhi = *(const half8*)(scb + kt * 64);
        half8 blo = *(const half8*)(scb + 2048 + kt * 64);
        acc = __builtin_amdgcn_mfma_f32_16x16x32_f16(vcur, bhi, acc, 0, 0, 0);
        acc = __builtin_amdgcn_mfma_f32_16x16x32_f16(vcur, blo, acc, 0, 0, 0);
        vcur = vnext;
    }
    {
        half8 bhi = *(const half8*)(scb + 31 * 64);
        half8 blo = *(const half8*)(scb + 2048 + 31 * 64);
        acc = __builtin_amdgcn_mfma_f32_16x16x32_f16(vcur, bhi, acc, 0, 0, 0);
        acc = __builtin_amdgcn_mfma_f32_16x16x32_f16(vcur, blo, acc, 0, 0, 0);
    }
    {
        float vsum = 0.f;
        #pragma unroll
        for (int w = 0; w < 16; ++w) vsum += wsum[w * TQ + qf];
        float r = 1.f / vsum;
        float* ob = out + ((size_t)(b * Qn + qbase + qf)) * Dv + wave * 16 + kc * 4;
        float4 o = { acc[0] * r, acc[1] * r, acc[2] * r, acc[3] * r };
        *(float4*)ob = o;
    }
}

extern "C" void kernel_launch(void* const* d_in, const int* in_sizes, int n_in,
                              void* d_out, int out_size, void* d_ws, size_t ws_size,
                              hipStream_t stream) {
    const float* queries = (const float*)d_in[0];
    const float* keys    = (const float*)d_in[1];
    const float* values  = (const float*)d_in[2];
    const float* W_q     = (const float*)d_in[3];
    const float* W_k     = (const float*)d_in[4];
    const float* w_v     = (const float*)d_in[5];
    float* out = (float*)d_out;

    float* Eqt = (float*)d_ws;                      // [B, H, Q]     1 MB
    float* Ekt = Eqt + Bn * Qn * Hh;                // [B, H, K]     1 MB
    _Float16* Vh = (_Float16*)(Ekt + Bn * Kn * Hh); // frag-order    2 MB

    prep_kernel<<<640, 256, 0, stream>>>(queries, W_q, keys, W_k, values,
                                         Eqt, Ekt, Vh);
    attn_kernel<<<Bn * (Qn / TQ), 1024, 0, stream>>>(Eqt, Ekt, Vh, w_v, out);
}